// Round 12
// baseline (2430.917 us; speedup 1.0000x reference)
//
#include <hip/hip_runtime.h>
#include <hip/hip_bf16.h>

constexpr int NN = 50000;
constexpr int EE = 200000;

__device__ __forceinline__ float b2f(unsigned short s) {
    union { unsigned u; float f; } c; c.u = ((unsigned)s) << 16; return c.f;
}
__device__ __forceinline__ unsigned short f2b(float f) {
    union { float f; unsigned u; } c; c.f = f;
    unsigned u = c.u + 0x7fffu + ((c.u >> 16) & 1u);
    return (unsigned short)(u >> 16);
}
// typed data load: f32m ? f32 : bf16
__device__ __forceinline__ float xv(const void* p, long i, int f32m) {
    return f32m ? ((const float*)p)[i] : b2f(((const unsigned short*)p)[i]);
}
// index load: i64m ? low word of int64 : int32
__device__ __forceinline__ int iv(const int* p, int i, int i64m) {
    return i64m ? p[2 * i] : p[i];
}

// flg[0]=1 if x is f32 (NaN/Inf bit patterns appear when misread as bf16);
// flg[1]=1 if indices are int64 (all high words of col0[0:64] are zero).
__global__ void k_detect(const unsigned short* x16, const int* c32, int* flg) {
    if (threadIdx.x != 0 || blockIdx.x != 0) return;
    int f32m = 0;
    for (int i = 0; i < 16384; i++) {
        if (((x16[i] >> 7) & 0xFF) == 0xFF) { f32m = 1; break; }
    }
    int i64m = 1;
    for (int i = 1; i < 128; i += 2) {
        if (c32[i] != 0) { i64m = 0; break; }
    }
    flg[0] = f32m; flg[1] = i64m;
}

__global__ void k_zero(unsigned* p, int n) {
    int i = blockIdx.x * 256 + threadIdx.x;
    if (i < n) p[i] = 0u;
}

// init: lgX[e] = 0.5*(x[col0[e]]+x[col1[e]]) stored bf16. Always: for edges
// with col0[e]!=col1[e], S[col1[e]] += relu(lgX[e] + x[col1[e]]).
// Line-graph collapse: the GINE aggregate for line-node j is S[col0[j]].
__global__ void k_s(const void* x, const int* col0, const int* col1,
                    unsigned short* lgX, float* S, const int* flg, int init) {
    int i = blockIdx.x * 256 + threadIdx.x;
    if (i >= EE * 128) return;
    int f32m = flg[0], i64m = flg[1];
    int e = i >> 7, k = i & 127;
    int a = iv(col0, e, i64m), b = iv(col1, e, i64m);
    float xb = xv(x, (long)b * 128 + k, f32m);
    float lg;
    if (init) {
        lg = 0.5f * (xv(x, (long)a * 128 + k, f32m) + xb);
        lgX[i] = f2b(lg);
    } else {
        lg = b2f(lgX[i]);
    }
    if (a != b) {
        float m = lg + xb;
        if (m > 0.0f) atomicAdd(&S[b * 128 + k], m);
    }
}

// One block per row e: row = lgX[e] (+ S[col0[e]] if addS) staged in LDS;
// Out[e,n] = act(sum_k row[k]*W[k,n] + bias[n]). In-place safe: each block
// reads only its own row before the sync, writes it after.
__global__ void k_mlp(const unsigned short* A, const float* S, const int* col0,
                      const void* W, const void* bias, unsigned short* Out,
                      const int* flg, int addS, int relu) {
    __shared__ float row[128];
    int f32m = flg[0], i64m = flg[1];
    int e = blockIdx.x, n = threadIdx.x;
    float v = b2f(A[e * 128 + n]);
    if (addS) v += S[iv(col0, e, i64m) * 128 + n];
    row[n] = v;
    __syncthreads();
    float acc = 0.0f;
    for (int k = 0; k < 128; k++) acc += row[k] * xv(W, k * 128 + n, f32m);
    acc += xv(bias, n, f32m);
    if (relu && acc < 0.0f) acc = 0.0f;
    Out[e * 128 + n] = f2b(acc);
}

// Final MLP2 fused with scatter-mean accumulation:
// v = row@W2 + b2; nodeSum[col1[e],n] += v; cnt[col1[e]] += 1.
__global__ void k_mlp_scatter(const unsigned short* A, const void* W,
                              const void* bias, const int* col1,
                              float* nodeSum, int* cnt, const int* flg) {
    __shared__ float row[128];
    int f32m = flg[0], i64m = flg[1];
    int e = blockIdx.x, n = threadIdx.x;
    row[n] = b2f(A[e * 128 + n]);
    __syncthreads();
    float acc = 0.0f;
    for (int k = 0; k < 128; k++) acc += row[k] * xv(W, k * 128 + n, f32m);
    acc += xv(bias, n, f32m);
    int b = iv(col1, e, i64m);
    atomicAdd(&nodeSum[b * 128 + n], acc);
    if (n == 0) atomicAdd(&cnt[b], 1);
}

// out = x + relu(nodeSum/cnt) (0 where cnt==0), written in the SAME dtype as
// the input x (f32 world -> f32 out, bf16 world -> bf16 out).
__global__ void LGNNGINELayer_12463995093126_kernel(
    const void* x, const float* nodeSum, const int* cnt, void* out,
    const int* flg) {
    int i = blockIdx.x * 256 + threadIdx.x;
    if (i >= NN * 128) return;
    int f32m = flg[0];
    int c = cnt[i >> 7];
    float g = 0.0f;
    if (c > 0) {
        g = nodeSum[i] / (float)c;
        if (g < 0.0f) g = 0.0f;
    }
    float r = xv(x, i, f32m) + g;
    if (f32m) ((float*)out)[i] = r;
    else ((unsigned short*)out)[i] = f2b(r);
}

extern "C" void kernel_launch(void* const* d_in, const int* in_sizes, int n_in,
                              void* d_out, int out_size, void* d_ws, size_t ws_size,
                              hipStream_t stream) {
    (void)in_sizes; (void)n_in; (void)out_size; (void)ws_size;
    const void* x  = d_in[0];
    const void* W1 = d_in[1];
    const void* b1 = d_in[2];
    const void* W2 = d_in[3];
    const void* b2 = d_in[4];
    const int* col0 = (const int*)d_in[5];
    const int* col1 = (const int*)d_in[6];

    // ws (77.0MB): lgX bf16 51.2 | S f32 25.6 (cycled S1->S2->nodeSum) | cnt | flg
    char* p = (char*)d_ws;
    unsigned short* lgX = (unsigned short*)p; p += (size_t)EE * 128 * 2;
    float* S = (float*)p; p += (size_t)NN * 128 * 4;
    int* cnt = (int*)p; p += (size_t)NN * 4;
    int* flg = (int*)p;

    int nd = NN * 128, zw = nd + NN;
    int zB = (zw + 255) / 256;
    int eB = (EE * 128) / 256;
    int nB = nd / 256;

    k_detect<<<1, 64, 0, stream>>>((const unsigned short*)x, col0, flg);

    // iteration 1
    k_zero<<<zB, 256, 0, stream>>>((unsigned*)S, zw);
    k_s<<<eB, 256, 0, stream>>>(x, col0, col1, lgX, S, flg, 1);
    k_mlp<<<EE, 128, 0, stream>>>(lgX, S, col0, W1, b1, lgX, flg, 1, 1);
    k_mlp<<<EE, 128, 0, stream>>>(lgX, S, col0, W2, b2, lgX, flg, 0, 0);

    // iteration 2 (S reused as S2)
    k_zero<<<zB, 256, 0, stream>>>((unsigned*)S, zw);
    k_s<<<eB, 256, 0, stream>>>(x, col0, col1, lgX, S, flg, 0);
    k_mlp<<<EE, 128, 0, stream>>>(lgX, S, col0, W1, b1, lgX, flg, 1, 1);

    // S reused as nodeSum; final MLP2 fused with node scatter
    k_zero<<<zB, 256, 0, stream>>>((unsigned*)S, zw);
    k_mlp_scatter<<<EE, 128, 0, stream>>>(lgX, W2, b2, col1, S, cnt, flg);
    LGNNGINELayer_12463995093126_kernel<<<nB, 256, 0, stream>>>(x, S, cnt, d_out, flg);
}

// Round 14
// 796.601 us; speedup vs baseline: 3.0516x; 3.0516x over previous
//
#include <hip/hip_runtime.h>
#include <hip/hip_bf16.h>

constexpr int NN = 50000;
constexpr int EE = 200000;
typedef __bf16 bf16x8 __attribute__((ext_vector_type(8)));
typedef float f32x4 __attribute__((ext_vector_type(4)));

__device__ __forceinline__ float b2f(unsigned short s) {
    union { unsigned u; float f; } c; c.u = ((unsigned)s) << 16; return c.f;
}
__device__ __forceinline__ unsigned short f2b(float f) {
    union { float f; unsigned u; } c; c.f = f;
    unsigned u = c.u + 0x7fffu + ((c.u >> 16) & 1u);
    return (unsigned short)(u >> 16);
}
__device__ __forceinline__ float xv(const void* p, long i, int f32m) {
    return f32m ? ((const float*)p)[i] : b2f(((const unsigned short*)p)[i]);
}
__device__ __forceinline__ int iv(const int* p, int i, int i64m) {
    return i64m ? p[2 * i] : p[i];
}

__global__ void k_detect(const unsigned short* x16, const int* c32, int* flg) {
    if (threadIdx.x != 0 || blockIdx.x != 0) return;
    int f32m = 0;
    for (int i = 0; i < 16384; i++)
        if (((x16[i] >> 7) & 0xFF) == 0xFF) { f32m = 1; break; }
    int i64m = 1;
    for (int i = 1; i < 128; i += 2)
        if (c32[i] != 0) { i64m = 0; break; }
    flg[0] = f32m; flg[1] = i64m;
}

__global__ void k_zero(unsigned* p, int n) {
    int i = blockIdx.x * 256 + threadIdx.x;
    if (i < n) p[i] = 0u;
}

// init: lgX[e] = 0.5*(x[col0[e]]+x[col1[e]]) stored bf16. Always, for non-self-
// loop edges: S[col1[e]] += relu(lgX[e]+x[col1[e]]). (line-graph collapse)
__global__ void k_s(const void* x, const int* col0, const int* col1,
                    unsigned short* lgX, float* S, const int* flg, int init) {
    int i = blockIdx.x * 256 + threadIdx.x;
    if (i >= EE * 128) return;
    int f32m = flg[0], i64m = flg[1];
    int e = i >> 7, k = i & 127;
    int a = iv(col0, e, i64m), b = iv(col1, e, i64m);
    float xb = xv(x, (long)b * 128 + k, f32m);
    float lg;
    if (init) { lg = 0.5f * (xv(x, (long)a * 128 + k, f32m) + xb); lgX[i] = f2b(lg); }
    else      { lg = b2f(lgX[i]); }
    if (a != b) {
        float m = lg + xb;
        if (m > 0.0f) atomicAdd(&S[b * 128 + k], m);
    }
}

// Pack W (either dtype) into bf16 MFMA B-fragment image:
// chunk=(t*4+c)*64+l ; Wf[chunk*8+j] = W[c*32+(l>>4)*8+j][t*16+(l&15)]
__global__ void k_wfrag(const void* W, unsigned short* Wf, const int* flg) {
    int f32m = flg[0];
    int chunk = blockIdx.x * 256 + threadIdx.x;
    if (chunk >= 2048) return;
    int l = chunk & 63, c = (chunk >> 6) & 3, t = chunk >> 8;
    int n = t * 16 + (l & 15), k0 = c * 32 + ((l >> 4) * 8);
    for (int j = 0; j < 8; j++) Wf[chunk * 8 + j] = f2b(xv(W, (long)(k0 + j) * 128 + n, f32m));
}

// 128x128-tile MFMA GEMM over edge rows, K=128. A = lgX (+S[col0] if addS),
// staged in A-fragment order. scat: fused scatter-mean epilogue by col1.
__global__ void k_gemm(const unsigned short* A, const float* S, const int* col0in,
                       const unsigned short* Wf, const void* bias, const int* col1in,
                       unsigned short* Out, float* nodeSum, int* cnt, const int* flg,
                       int addS, int relu, int scat) {
    __shared__ unsigned short Al[16384], Bl[16384];
    int f32m = flg[0], i64m = flg[1];
    int tid = threadIdx.x;
    int e0 = blockIdx.x * 128;
    for (int i = 0; i < 8; i++)
        ((uint4*)Bl)[i * 256 + tid] = ((const uint4*)Wf)[i * 256 + tid];
    for (int i = 0; i < 8; i++) {
        int chunk = i * 256 + tid;
        int l = chunk & 63, c = (chunk >> 6) & 3, r = chunk >> 8;
        int m = r * 16 + (l & 15), k0 = c * 32 + ((l >> 4) * 8);
        int e = e0 + m;
        unsigned short v[8];
        if (e < EE) {
            const unsigned short* ap = A + (size_t)e * 128 + k0;
            if (addS) {
                const float* sp = S + (size_t)iv(col0in, e, i64m) * 128 + k0;
                for (int j = 0; j < 8; j++) v[j] = f2b(b2f(ap[j]) + sp[j]);
            } else
                for (int j = 0; j < 8; j++) v[j] = ap[j];
        } else
            for (int j = 0; j < 8; j++) v[j] = 0;
        for (int j = 0; j < 8; j++) Al[chunk * 8 + j] = v[j];
    }
    __syncthreads();
    int w = tid >> 6, l = tid & 63;
    int rt0 = (w & 1) * 4, ct0 = (w >> 1) * 4;
    f32x4 acc[4][4];
    for (int i = 0; i < 4; i++)
        for (int j = 0; j < 4; j++)
            for (int r = 0; r < 4; r++) acc[i][j][r] = 0.0f;
    for (int c = 0; c < 4; c++) {
        bf16x8 af[4], bf[4];
        for (int i = 0; i < 4; i++) af[i] = *(const bf16x8*)(Al + (((rt0 + i) * 4 + c) * 64 + l) * 8);
        for (int j = 0; j < 4; j++) bf[j] = *(const bf16x8*)(Bl + (((ct0 + j) * 4 + c) * 64 + l) * 8);
        for (int i = 0; i < 4; i++)
            for (int j = 0; j < 4; j++)
                acc[i][j] = __builtin_amdgcn_mfma_f32_16x16x32_bf16(af[i], bf[j], acc[i][j], 0, 0, 0);
    }
    int lq = l >> 4, ln = l & 15;   // C/D: col=lane&15, row=(lane>>4)*4+reg
    for (int j = 0; j < 4; j++) {
        int n = (ct0 + j) * 16 + ln;
        float bv = xv(bias, n, f32m);
        for (int i = 0; i < 4; i++) {
            int eb = e0 + (rt0 + i) * 16 + lq * 4;
            for (int rg = 0; rg < 4; rg++) {
                int e = eb + rg;
                if (e >= EE) continue;
                float v = acc[i][j][rg] + bv;
                if (relu && v < 0.0f) v = 0.0f;
                if (scat) {
                    int b = iv(col1in, e, i64m);
                    atomicAdd(&nodeSum[(size_t)b * 128 + n], v);
                    // cnt: exactly once per edge -> only the ct0==0 column-half
                    // (R12 bug: both column-half waves incremented -> cnt was 2x,
                    // halving gx; absmax was 111 = ref_max/2)
                    if (j == 0 && ln == 0 && ct0 == 0) atomicAdd(&cnt[b], 1);
                } else
                    Out[(size_t)e * 128 + n] = f2b(v);
            }
        }
    }
}

// out = x + relu(nodeSum/cnt) (0 where cnt==0), same dtype as x.
__global__ void LGNNGINELayer_12463995093126_kernel(
    const void* x, const float* nodeSum, const int* cnt, void* out, const int* flg) {
    int i = blockIdx.x * 256 + threadIdx.x;
    if (i >= NN * 128) return;
    int f32m = flg[0];
    int c = cnt[i >> 7];
    float g = 0.0f;
    if (c > 0) { g = nodeSum[i] / (float)c; if (g < 0.0f) g = 0.0f; }
    float r = xv(x, i, f32m) + g;
    if (f32m) ((float*)out)[i] = r;
    else ((unsigned short*)out)[i] = f2b(r);
}

extern "C" void kernel_launch(void* const* d_in, const int* in_sizes, int n_in,
                              void* d_out, int out_size, void* d_ws, size_t ws_size,
                              hipStream_t stream) {
    (void)in_sizes; (void)n_in; (void)out_size; (void)ws_size;
    const void* x = d_in[0];
    const void* W1 = d_in[1];
    const void* b1 = d_in[2];
    const void* W2 = d_in[3];
    const void* b2 = d_in[4];
    const int* col0 = (const int*)d_in[5];
    const int* col1 = (const int*)d_in[6];

    // ws: lgX bf16 51.2MB | S f32 25.6MB (S1->S2->nodeSum) | cnt | flg | Wf1 | Wf2
    char* p = (char*)d_ws;
    unsigned short* lgX = (unsigned short*)p; p += (size_t)EE * 128 * 2;
    float* S = (float*)p; p += (size_t)NN * 128 * 4;
    int* cnt = (int*)p; p += (size_t)NN * 4;
    int* flg = (int*)p; p += 256;
    unsigned short* Wf1 = (unsigned short*)p; p += 16384 * 2;
    unsigned short* Wf2 = (unsigned short*)p;

    int nd = NN * 128, zw = nd + NN;
    int zB = (zw + 255) / 256;
    int eB = (EE * 128) / 256;
    int nB = nd / 256;
    int gB = (EE + 127) / 128;

    k_detect<<<1, 64, 0, stream>>>((const unsigned short*)x, col0, flg);
    k_wfrag<<<8, 256, 0, stream>>>(W1, Wf1, flg);
    k_wfrag<<<8, 256, 0, stream>>>(W2, Wf2, flg);

    // iteration 1
    k_zero<<<zB, 256, 0, stream>>>((unsigned*)S, zw);
    k_s<<<eB, 256, 0, stream>>>(x, col0, col1, lgX, S, flg, 1);
    k_gemm<<<gB, 256, 0, stream>>>(lgX, S, col0, Wf1, b1, col1, lgX, S, cnt, flg, 1, 1, 0);
    k_gemm<<<gB, 256, 0, stream>>>(lgX, S, col0, Wf2, b2, col1, lgX, S, cnt, flg, 0, 0, 0);

    // iteration 2
    k_zero<<<zB, 256, 0, stream>>>((unsigned*)S, zw);
    k_s<<<eB, 256, 0, stream>>>(x, col0, col1, lgX, S, flg, 0);
    k_gemm<<<gB, 256, 0, stream>>>(lgX, S, col0, Wf1, b1, col1, lgX, S, cnt, flg, 1, 1, 0);

    // final MLP2 fused with scatter-mean into S (=nodeSum) + cnt
    k_zero<<<zB, 256, 0, stream>>>((unsigned*)S, zw);
    k_gemm<<<gB, 256, 0, stream>>>(lgX, S, col0, Wf2, b2, col1, lgX, S, cnt, flg, 0, 0, 1);
    LGNNGINELayer_12463995093126_kernel<<<nB, 256, 0, stream>>>(x, S, cnt, d_out, flg);
}

// Round 15
// 689.711 us; speedup vs baseline: 3.5245x; 1.1550x over previous
//
#include <hip/hip_runtime.h>
#include <hip/hip_bf16.h>

constexpr int NN = 50000;
constexpr int EE = 200000;
typedef __bf16 bf16x8 __attribute__((ext_vector_type(8)));
typedef float f32x4 __attribute__((ext_vector_type(4)));

__device__ __forceinline__ float b2f(unsigned short s) {
    union { unsigned u; float f; } c; c.u = ((unsigned)s) << 16; return c.f;
}
__device__ __forceinline__ unsigned short f2b(float f) {
    union { float f; unsigned u; } c; c.f = f;
    unsigned u = c.u + 0x7fffu + ((c.u >> 16) & 1u);
    return (unsigned short)(u >> 16);
}
__device__ __forceinline__ float xv(const void* p, long i, int f32m) {
    return f32m ? ((const float*)p)[i] : b2f(((const unsigned short*)p)[i]);
}
__device__ __forceinline__ int iv(const int* p, int i, int i64m) {
    return i64m ? p[2 * i] : p[i];
}

__global__ void k_detect(const unsigned short* x16, const int* c32, int* flg) {
    if (threadIdx.x != 0 || blockIdx.x != 0) return;
    int f32m = 0;
    for (int i = 0; i < 16384; i++)
        if (((x16[i] >> 7) & 0xFF) == 0xFF) { f32m = 1; break; }
    int i64m = 1;
    for (int i = 1; i < 128; i += 2)
        if (c32[i] != 0) { i64m = 0; break; }
    flg[0] = f32m; flg[1] = i64m;
}

__global__ void k_zero(unsigned* p, int n) {
    int i = blockIdx.x * 256 + threadIdx.x;
    if (i < n) p[i] = 0u;
}

// init: lgX[e] = 0.5*(x[col0[e]]+x[col1[e]]) stored bf16. Always, for non-self-
// loop edges: S[col1[e]] += relu(lgX[e]+x[col1[e]]). (line-graph collapse)
__global__ void k_s(const void* x, const int* col0, const int* col1,
                    unsigned short* lgX, float* S, const int* flg, int init) {
    int i = blockIdx.x * 256 + threadIdx.x;
    if (i >= EE * 128) return;
    int f32m = flg[0], i64m = flg[1];
    int e = i >> 7, k = i & 127;
    int a = iv(col0, e, i64m), b = iv(col1, e, i64m);
    float xb = xv(x, (long)b * 128 + k, f32m);
    float lg;
    if (init) { lg = 0.5f * (xv(x, (long)a * 128 + k, f32m) + xb); lgX[i] = f2b(lg); }
    else      { lg = b2f(lgX[i]); }
    if (a != b) {
        float m = lg + xb;
        if (m > 0.0f) atomicAdd(&S[b * 128 + k], m);
    }
}

// Pack W into bf16 MFMA B-fragment image: chunk=(t*4+c)*64+l ;
// Wf[chunk*8+j] = W[c*32+(l>>4)*8+j][t*16+(l&15)]
__global__ void k_wfrag(const void* W, unsigned short* Wf, const int* flg) {
    int f32m = flg[0];
    int chunk = blockIdx.x * 256 + threadIdx.x;
    if (chunk >= 2048) return;
    int l = chunk & 63, c = (chunk >> 6) & 3, t = chunk >> 8;
    int n = t * 16 + (l & 15), k0 = c * 32 + ((l >> 4) * 8);
    for (int j = 0; j < 8; j++) Wf[chunk * 8 + j] = f2b(xv(W, (long)(k0 + j) * 128 + n, f32m));
}

// Fused 2-layer MLP over a 128-row edge tile, K=128:
// Out = (relu((lgX + S[col0]) @ W1 + b1)) @ W2 + b2, Out stored in-place (bf16).
// H stays in LDS (A-fragment order); C2 round-trips LDS row-major for coalesced stores.
__global__ void k_fused(const unsigned short* A, const float* S, const int* col0in,
                        const unsigned short* Wf1, const unsigned short* Wf2,
                        const void* bias1, const void* bias2,
                        unsigned short* Out, const int* flg) {
    __shared__ unsigned short Al[16384], Bl[16384];
    int f32m = flg[0], i64m = flg[1];
    int tid = threadIdx.x;
    int e0 = blockIdx.x * 128;
    for (int i = 0; i < 8; i++)
        ((uint4*)Bl)[i * 256 + tid] = ((const uint4*)Wf1)[i * 256 + tid];
    for (int i = 0; i < 8; i++) {
        int chunk = i * 256 + tid;
        int l = chunk & 63, c = (chunk >> 6) & 3, r = chunk >> 8;
        int m = r * 16 + (l & 15), k0 = c * 32 + ((l >> 4) * 8);
        int e = e0 + m;
        unsigned short v[8];
        if (e < EE) {
            const unsigned short* ap = A + (size_t)e * 128 + k0;
            const float* sp = S + (size_t)iv(col0in, e, i64m) * 128 + k0;
            for (int j = 0; j < 8; j++) v[j] = f2b(b2f(ap[j]) + sp[j]);
        } else
            for (int j = 0; j < 8; j++) v[j] = 0;
        for (int j = 0; j < 8; j++) Al[chunk * 8 + j] = v[j];
    }
    __syncthreads();
    int w = tid >> 6, l = tid & 63;
    int rt0 = (w & 1) * 4, ct0 = (w >> 1) * 4;
    int lq = l >> 4, ln = l & 15;
    f32x4 acc[4][4];
    for (int i = 0; i < 4; i++)
        for (int j = 0; j < 4; j++)
            for (int r = 0; r < 4; r++) acc[i][j][r] = 0.0f;
    for (int c = 0; c < 4; c++) {
        bf16x8 af[4], bf[4];
        for (int i = 0; i < 4; i++) af[i] = *(const bf16x8*)(Al + (((rt0 + i) * 4 + c) * 64 + l) * 8);
        for (int j = 0; j < 4; j++) bf[j] = *(const bf16x8*)(Bl + (((ct0 + j) * 4 + c) * 64 + l) * 8);
        for (int i = 0; i < 4; i++)
            for (int j = 0; j < 4; j++)
                acc[i][j] = __builtin_amdgcn_mfma_f32_16x16x32_bf16(af[i], bf[j], acc[i][j], 0, 0, 0);
    }
    __syncthreads();   // all MFMA1 reads of Al/Bl done
    // W2 frags -> Bl; H = relu(C1 + b1) -> Al in A-fragment order:
    // element (m,k=n): Al[(( (m>>4)*4 + (n>>5) )*64 + ((n>>3)&3)*16 + (m&15))*8 + (n&7)]
    for (int i = 0; i < 8; i++)
        ((uint4*)Bl)[i * 256 + tid] = ((const uint4*)Wf2)[i * 256 + tid];
    for (int j = 0; j < 4; j++) {
        int n = (ct0 + j) * 16 + ln;
        float bv = xv(bias1, n, f32m);
        int c = n >> 5, lo = ((n >> 3) & 3) * 16, j2 = n & 7;
        for (int i = 0; i < 4; i++) {
            int r = rt0 + i;
            for (int rg = 0; rg < 4; rg++) {
                float h = acc[i][j][rg] + bv;
                if (h < 0.0f) h = 0.0f;
                Al[((r * 4 + c) * 64 + lo + lq * 4 + rg) * 8 + j2] = f2b(h);
            }
        }
    }
    __syncthreads();
    for (int i = 0; i < 4; i++)
        for (int j = 0; j < 4; j++)
            for (int r = 0; r < 4; r++) acc[i][j][r] = 0.0f;
    for (int c = 0; c < 4; c++) {
        bf16x8 af[4], bf[4];
        for (int i = 0; i < 4; i++) af[i] = *(const bf16x8*)(Al + (((rt0 + i) * 4 + c) * 64 + l) * 8);
        for (int j = 0; j < 4; j++) bf[j] = *(const bf16x8*)(Bl + (((ct0 + j) * 4 + c) * 64 + l) * 8);
        for (int i = 0; i < 4; i++)
            for (int j = 0; j < 4; j++)
                acc[i][j] = __builtin_amdgcn_mfma_f32_16x16x32_bf16(af[i], bf[j], acc[i][j], 0, 0, 0);
    }
    __syncthreads();   // before overwriting Al as row-major C2
    for (int j = 0; j < 4; j++) {
        int n = (ct0 + j) * 16 + ln;
        float bv = xv(bias2, n, f32m);
        for (int i = 0; i < 4; i++) {
            int mb = (rt0 + i) * 16 + lq * 4;
            for (int rg = 0; rg < 4; rg++)
                Al[(mb + rg) * 128 + n] = f2b(acc[i][j][rg] + bv);
        }
    }
    __syncthreads();
    // coalesced store: Al row-major == lgX tile layout
    for (int i = 0; i < 8; i++) {
        int idx = i * 256 + tid;
        if (e0 + (idx >> 4) < EE)
            ((uint4*)Out)[(size_t)e0 * 16 + idx] = ((const uint4*)Al)[idx];
    }
}

// nodeSum[col1[e]] += lgX[e]; cnt[col1[e]] += 1 (once per edge)
__global__ void k_nodes(const unsigned short* lgX, const int* col1,
                        float* S, int* cnt, const int* flg) {
    int i = blockIdx.x * 256 + threadIdx.x;
    if (i >= EE * 128) return;
    int i64m = flg[1];
    int e = i >> 7, k = i & 127;
    int b = iv(col1, e, i64m);
    atomicAdd(&S[(size_t)b * 128 + k], b2f(lgX[i]));
    if (k == 0) atomicAdd(&cnt[b], 1);
}

// out = x + relu(nodeSum/cnt) (0 where cnt==0), same dtype as x.
__global__ void LGNNGINELayer_12463995093126_kernel(
    const void* x, const float* nodeSum, const int* cnt, void* out, const int* flg) {
    int i = blockIdx.x * 256 + threadIdx.x;
    if (i >= NN * 128) return;
    int f32m = flg[0];
    int c = cnt[i >> 7];
    float g = 0.0f;
    if (c > 0) { g = nodeSum[i] / (float)c; if (g < 0.0f) g = 0.0f; }
    float r = xv(x, i, f32m) + g;
    if (f32m) ((float*)out)[i] = r;
    else ((unsigned short*)out)[i] = f2b(r);
}

extern "C" void kernel_launch(void* const* d_in, const int* in_sizes, int n_in,
                              void* d_out, int out_size, void* d_ws, size_t ws_size,
                              hipStream_t stream) {
    (void)in_sizes; (void)n_in; (void)out_size; (void)ws_size;
    const void* x = d_in[0];
    const void* W1 = d_in[1];
    const void* b1 = d_in[2];
    const void* W2 = d_in[3];
    const void* b2 = d_in[4];
    const int* col0 = (const int*)d_in[5];
    const int* col1 = (const int*)d_in[6];

    // ws: lgX bf16 51.2MB | S f32 25.6MB (S1->S2->nodeSum) | cnt | flg | Wf1 | Wf2
    char* p = (char*)d_ws;
    unsigned short* lgX = (unsigned short*)p; p += (size_t)EE * 128 * 2;
    float* S = (float*)p; p += (size_t)NN * 128 * 4;
    int* cnt = (int*)p; p += (size_t)NN * 4;
    int* flg = (int*)p; p += 256;
    unsigned short* Wf1 = (unsigned short*)p; p += 16384 * 2;
    unsigned short* Wf2 = (unsigned short*)p;

    int nd = NN * 128, zw = nd + NN;
    int zB = (zw + 255) / 256;
    int eB = (EE * 128) / 256;
    int nB = nd / 256;
    int gB = (EE + 127) / 128;

    k_detect<<<1, 64, 0, stream>>>((const unsigned short*)x, col0, flg);
    k_wfrag<<<8, 256, 0, stream>>>(W1, Wf1, flg);
    k_wfrag<<<8, 256, 0, stream>>>(W2, Wf2, flg);

    // iteration 1: aggregate S1, fused 2-layer MLP (in-place lgX)
    k_zero<<<zB, 256, 0, stream>>>((unsigned*)S, zw);
    k_s<<<eB, 256, 0, stream>>>(x, col0, col1, lgX, S, flg, 1);
    k_fused<<<gB, 256, 0, stream>>>(lgX, S, col0, Wf1, Wf2, b1, b2, lgX, flg);

    // iteration 2
    k_zero<<<zB, 256, 0, stream>>>((unsigned*)S, zw);
    k_s<<<eB, 256, 0, stream>>>(x, col0, col1, lgX, S, flg, 0);
    k_fused<<<gB, 256, 0, stream>>>(lgX, S, col0, Wf1, Wf2, b1, b2, lgX, flg);

    // scatter-mean back to nodes + residual/relu
    k_zero<<<zB, 256, 0, stream>>>((unsigned*)S, zw);
    k_nodes<<<eB, 256, 0, stream>>>(lgX, col1, S, cnt, flg);
    LGNNGINELayer_12463995093126_kernel<<<nB, 256, 0, stream>>>(x, S, cnt, d_out, flg);
}